// Round 10
// baseline (109.221 us; speedup 1.0000x reference)
//
#include <hip/hip_runtime.h>
#include <hip/hip_bf16.h>

#define NN 4096

typedef unsigned short u16;
typedef __attribute__((ext_vector_type(8))) short bf16x8;
typedef __attribute__((ext_vector_type(4))) float f32x4;

// fp32 -> bf16 round-to-nearest-even (inputs finite N(0,1))
static __device__ __forceinline__ u16 f2bf(float x) {
  unsigned u = __float_as_uint(x);
  u += 0x7fff + ((u >> 16) & 1);
  return (u16)(u >> 16);
}

// async global->LDS, 16B per lane; LDS dest = wave-uniform base + lane*16
static __device__ __forceinline__ void gload_lds16(const void* g, void* l) {
  __builtin_amdgcn_global_load_lds(
      (const __attribute__((address_space(1))) void*)g,
      (__attribute__((address_space(3))) void*)l, 16, 0, 0);
}

// F(M) = sum_{j=0}^{M-1} floor(j/CS)
static __device__ __forceinline__ int Fpre(int M, int CS) {
  if (M <= 0) return 0;
  const int q = (M - 1) / CS, r = (M - 1) % CS;
  return CS * q * (q - 1) / 2 + q * (r + 1);
}

// ---------------------------------------------------------------------------
// Pass 1 (fused, trimmed grid = 3136): blocks [0,1024): convert A (tril bf16)
// for 128-blocks kb<=bi, zero strict-upper C blocks for kb>bi. Blocks
// [1024,3136): convert B -> Bt over ONLY the 2112 needed 64x64 tiles
// (pair-decoded lower-triangular 128-block region).
// ---------------------------------------------------------------------------
__global__ __launch_bounds__(256) void convert_fused(
    const float* __restrict__ A, const float* __restrict__ B,
    u16* __restrict__ Ab, u16* __restrict__ Bt, float* __restrict__ C) {
  __shared__ float t[64][65];
  const int blk = blockIdx.x;
  const int tid = threadIdx.x;

  if (blk < 1024) {  // ---- A path: 128x128 block (bi, kb) ----
    const int kb = blk & 31, bi = blk >> 5;
    if (kb > bi) {  // zero C block (bi, kb)
      const float4 z = {0.f, 0.f, 0.f, 0.f};
      const int rr = tid >> 5, c4 = (tid & 31);
#pragma unroll
      for (int p = 0; p < 16; ++p)
        ((float4*)&C[(long)(bi * 128 + p * 8 + rr) * NN + kb * 128])[c4] = z;
      return;
    }
    const int rr = tid >> 5;
    const int c4 = (tid & 31) * 4;
    const bool diag = (kb == bi);
#pragma unroll
    for (int p = 0; p < 16; ++p) {
      const int row = p * 8 + rr;
      const long off = (long)(bi * 128 + row) * NN + kb * 128 + c4;
      float4 v = *(const float4*)&A[off];
      ushort4 o;
      if (diag) {
        const int i = bi * 128 + row, k = kb * 128 + c4;
        o.x = (k + 0 <= i) ? f2bf(v.x) : (u16)0;
        o.y = (k + 1 <= i) ? f2bf(v.y) : (u16)0;
        o.z = (k + 2 <= i) ? f2bf(v.z) : (u16)0;
        o.w = (k + 3 <= i) ? f2bf(v.w) : (u16)0;
      } else {
        o.x = f2bf(v.x); o.y = f2bf(v.y); o.z = f2bf(v.z); o.w = f2bf(v.w);
      }
      *(ushort4*)&Ab[off] = o;
    }
    return;
  }

  // ---- B path: pair-decoded 64x64 transpose tile (only needed ones) ----
  const int t4 = blk - 1024;  // 0..2111 = 528 pairs x 4 subtiles
  int prem = t4 >> 2, N = 0;
  while (prem >= 32 - N) { prem -= 32 - N; ++N; }
  const int K = N + prem;     // N <= K: 128-block (n=N, k=K) is needed
  const int sub = t4 & 3;
  const int n64 = 2 * N + (sub & 1);
  const int k64 = 2 * K + (sub >> 1);

  const int n0 = n64 * 64;
  const int k0 = k64 * 64;

  if (n0 > k0 + 63) {  // needed block, 64-tile fully above diagonal -> zeros
    const int n = tid >> 3;
    const int kc = (tid & 7) * 8;
    const uint4 z = {0u, 0u, 0u, 0u};
#pragma unroll
    for (int p = 0; p < 2; ++p)
      *(uint4*)&Bt[(long)(n0 + n + p * 32) * NN + k0 + kc] = z;
    return;
  }

#pragma unroll
  for (int p = 0; p < 4; ++p) {
    const int r = (tid >> 4) + p * 16;
    const int c = (tid & 15) * 4;
    float4 v = *(const float4*)&B[(long)(k0 + r) * NN + n0 + c];
    const int kg = k0 + r;
    t[r][c + 0] = (n0 + c + 0 <= kg) ? v.x : 0.f;
    t[r][c + 1] = (n0 + c + 1 <= kg) ? v.y : 0.f;
    t[r][c + 2] = (n0 + c + 2 <= kg) ? v.z : 0.f;
    t[r][c + 3] = (n0 + c + 3 <= kg) ? v.w : 0.f;
  }
  __syncthreads();

#pragma unroll
  for (int p = 0; p < 2; ++p) {
    const int n = (tid >> 3) + p * 32;
    const int kc = (tid & 7) * 8;
    union { u16 h[8]; uint4 v; } pk;
#pragma unroll
    for (int j = 0; j < 8; ++j) pk.h[j] = f2bf(t[kc + j][n]);
    *(uint4*)&Bt[(long)(n0 + n) * NN + k0 + kc] = pk.v;
  }
}

// ---------------------------------------------------------------------------
// Pass 2: lower-tri bf16 MFMA GEMM, 64x128 tile, 128 threads (2 waves),
// SINGLE 24 KB LDS buffer -> 6 blocks/CU = 12 waves/CU (m97 regime: the
// per-step vmcnt(0)+barrier drain is hidden by co-resident blocks at
// different phases, m114). One block per (tile, chunk) item, decoded from
// blockIdx.x longest-K-first. Chunk = CSK=2H K64-steps. Swizzled staging
// (pre-swizzled global source col) + XOR'd read slot -> 0 bank conflicts.
// Wave w computes rows [bi*64, +64) x cols [bj*128 + w*64, +64).
// ---------------------------------------------------------------------------
__global__ __launch_bounds__(128, 3) void gemm_tril(
    const u16* __restrict__ Ab, const u16* __restrict__ Bt,
    float* __restrict__ C, float* __restrict__ P, int H) {
  __shared__ u16 As[64 * 64];    // 8 KB
  __shared__ u16 Bs[128 * 64];   // 16 KB

  const int tid = threadIdx.x;
  const int lane = tid & 63;
  const int wid = tid >> 6;               // 0..1
  const int sm = lane >> 3;               // staging row within 8-row chunk
  const int sks = ((lane & 7) ^ sm) * 8;  // pre-swizzled source col (u16)
  const int rsel = lane & 7;              // fragment row & 7

  // ---- decode blockIdx.x -> (bi, bj, chunk); rows (64-row) longest-first.
  // items(row bi) = (m+1) + Fpre(m+1,H), m = bi>>1; chunks(bj) = 1+(m-bj)/H.
  int rem = blockIdx.x, bi = 63, m = 31, slabpre = 0;
  for (int s = 0; s < 64; ++s) {
    bi = 63 - s; m = bi >> 1;
    const int fp = Fpre(m + 1, H);
    const int g = (m + 1) + fp;
    if (rem < g) break;
    rem -= g; slabpre += fp;
  }
  int bj = 0;
  for (;;) {
    const int c = 1 + (m - bj) / H;
    if (rem < c) break;
    rem -= c; ++bj;
  }
  const int chunk = rem;
  const int L = bi + 1 - 2 * bj;  // K64-steps of this tile
  const int CSK = 2 * H;
  const int start = chunk * CSK;
  const int nk = min(CSK, L - start);
  const int rA = bi * 64;
  const int rB = bj * 128;
  const long kbase = (long)bj * 128 + (long)start * 64;

  f32x4 acc[4][4];
#pragma unroll
  for (int i = 0; i < 4; ++i)
#pragma unroll
    for (int j = 0; j < 4; ++j) acc[i][j] = (f32x4){0.f, 0.f, 0.f, 0.f};

  for (int kt = 0; kt < nk; ++kt) {
    const long k0 = kbase + (long)kt * 64;
#pragma unroll
    for (int c = 0; c < 4; ++c) {  // A: 8 chunks of 8 rows x 64 bf16
      const int ch = wid * 4 + c;
      gload_lds16(Ab + ((long)(rA + ch * 8 + sm) * NN + k0 + sks),
                  &As[ch * 512]);
    }
#pragma unroll
    for (int c = 0; c < 8; ++c) {  // B: 16 chunks
      const int ch = wid * 8 + c;
      gload_lds16(Bt + ((long)(rB + ch * 8 + sm) * NN + k0 + sks),
                  &Bs[ch * 512]);
    }
    __syncthreads();  // drains vmcnt(0); co-resident blocks cover the stall

    bf16x8 a[2][4], b[2][4];
#pragma unroll
    for (int kk = 0; kk < 2; ++kk)
#pragma unroll
      for (int q = 0; q < 4; ++q) {
        const int fr = q * 16 + (lane & 15);
        const int slot = ((kk * 4 + (lane >> 4)) ^ rsel) * 8;  // swizzled col
        a[kk][q] = *(const bf16x8*)&As[fr * 64 + slot];
        b[kk][q] = *(const bf16x8*)&Bs[(wid * 64 + fr) * 64 + slot];
      }
#pragma unroll
    for (int kk = 0; kk < 2; ++kk)
#pragma unroll
      for (int m4 = 0; m4 < 4; ++m4)
#pragma unroll
        for (int n4 = 0; n4 < 4; ++n4)
          acc[m4][n4] = __builtin_amdgcn_mfma_f32_16x16x32_bf16(
              a[kk][m4], b[kk][n4], acc[m4][n4], 0, 0, 0);
    __syncthreads();  // LDS free for next K-step
  }

  // ---- epilogue: C/D layout col=lane&15, row=(lane>>4)*4+r ----
  const int lrow = (lane >> 4) * 4;
  const int lcol = wid * 64 + (lane & 15);
  if (chunk == 0) {
    const bool diag = (bj == m);  // diag tiles: L<=2 -> always single-chunk
#pragma unroll
    for (int m4 = 0; m4 < 4; ++m4)
#pragma unroll
      for (int n4 = 0; n4 < 4; ++n4)
#pragma unroll
        for (int r = 0; r < 4; ++r) {
          const int gi = rA + lrow + m4 * 16 + r;
          const int gj = rB + lcol + n4 * 16;
          float v = acc[m4][n4][r];
          if (diag && gj > gi) v = 0.f;
          C[(long)gi * NN + gj] = v;
        }
  } else {
    const int slabidx =
        slabpre + (Fpre(m + 1, H) - Fpre(m - bj + 1, H)) + (chunk - 1);
    float* slab = P + (long)slabidx * 8192;  // 64x128 fp32 = 32 KB
#pragma unroll
    for (int m4 = 0; m4 < 4; ++m4)
#pragma unroll
      for (int n4 = 0; n4 < 4; ++n4)
#pragma unroll
        for (int r = 0; r < 4; ++r)
          slab[(lrow + m4 * 16 + r) * 128 + lcol + n4 * 16] = acc[m4][n4][r];
  }
}

// ---------------------------------------------------------------------------
// Pass 3: add partial slabs into C. Grid = multi-chunk tiles only:
// per row count max(0, m-H+1); total (32-H)(33-H)... = 600 (H=8) / 272 (H=16).
// ---------------------------------------------------------------------------
__global__ __launch_bounds__(256) void reduce_partials(
    float* __restrict__ C, const float* __restrict__ P, int H) {
  int rem = blockIdx.x, bi = 63, m = 31, slabpre = 0;
  for (int s = 0; s < 64; ++s) {
    bi = 63 - s; m = bi >> 1;
    const int g = (m - H + 1 > 0) ? (m - H + 1) : 0;
    if (rem < g) break;
    rem -= g; slabpre += Fpre(m + 1, H);
  }
  const int bj = rem;                 // 0..m-H -> nch >= 2
  const int nch = 1 + (m - bj) / H;
  const int slaboff = slabpre + (Fpre(m + 1, H) - Fpre(m - bj + 1, H));

  const int tid = threadIdx.x;
#pragma unroll
  for (int p = 0; p < 8; ++p) {
    const int idx = p * 256 + tid;    // float4 index in 64x128 tile (0..2047)
    const int row = idx >> 5;
    const int col = (idx & 31) * 4;
    const long coff = (long)(bi * 64 + row) * NN + bj * 128 + col;
    float4 acc = *(const float4*)&C[coff];
    for (int e = 0; e < nch - 1; ++e) {
      const float4 q =
          *(const float4*)&P[(long)(slaboff + e) * 8192 + row * 128 + col];
      acc.x += q.x; acc.y += q.y; acc.z += q.z; acc.w += q.w;
    }
    *(float4*)&C[coff] = acc;
  }
}

// ---------------------------------------------------------------------------
// Fallback (ws too small): naive fp32.
// ---------------------------------------------------------------------------
__global__ void naive_tril(const float* __restrict__ A,
                           const float* __restrict__ B, float* __restrict__ C) {
  const int j = blockIdx.x * 256 + threadIdx.x;
  const int i = blockIdx.y;
  float s = 0.f;
  for (int k = j; k <= i; ++k) s += A[(long)i * NN + k] * B[(long)k * NN + j];
  C[(long)i * NN + j] = s;
}

extern "C" void kernel_launch(void* const* d_in, const int* in_sizes, int n_in,
                              void* d_out, int out_size, void* d_ws,
                              size_t ws_size, hipStream_t stream) {
  const float* A = (const float*)d_in[0];
  const float* B = (const float*)d_in[1];
  float* C = (float*)d_out;

  const size_t opbytes = (size_t)2 * NN * NN * sizeof(u16);  // 64 MB operands
  // tiers (H = CSK/2; slab = 64x128 fp32 = 32 KB):
  //   H=8:  2000 items, 944 slabs (30.9 MB), 600 reduce tiles
  //   H=16: 1328 items, 272 slabs (8.9 MB), 272 reduce tiles
  //   H=32: 1056 items, 0 slabs
  const size_t needH8 = opbytes + (size_t)944 * 32768;
  const size_t needH16 = opbytes + (size_t)272 * 32768;

  if (ws_size < opbytes) {
    naive_tril<<<dim3(16, NN), 256, 0, stream>>>(A, B, C);
    return;
  }

  int H, nitems, nred;
  if (ws_size >= needH8)       { H = 8;  nitems = 2000; nred = 600; }
  else if (ws_size >= needH16) { H = 16; nitems = 1328; nred = 272; }
  else                         { H = 32; nitems = 1056; nred = 0; }

  u16* Ab = (u16*)d_ws;
  u16* Bt = Ab + (long)NN * NN;
  float* P = (float*)((char*)d_ws + opbytes);

  convert_fused<<<3136, 256, 0, stream>>>(A, B, Ab, Bt, C);
  gemm_tril<<<nitems, 128, 0, stream>>>(Ab, Bt, C, P, H);
  if (nred > 0) reduce_partials<<<nred, 256, 0, stream>>>(C, P, H);
}

// Round 11
// 100.178 us; speedup vs baseline: 1.0903x; 1.0903x over previous
//
#include <hip/hip_runtime.h>
#include <hip/hip_bf16.h>

#define NN 4096

typedef unsigned short u16;
typedef __attribute__((ext_vector_type(8))) short bf16x8;
typedef __attribute__((ext_vector_type(4))) float f32x4;

// fp32 -> bf16 round-to-nearest-even (inputs finite N(0,1))
static __device__ __forceinline__ u16 f2bf(float x) {
  unsigned u = __float_as_uint(x);
  u += 0x7fff + ((u >> 16) & 1);
  return (u16)(u >> 16);
}

// async global->LDS, 16B per lane; LDS dest = wave-uniform base + lane*16
static __device__ __forceinline__ void gload_lds16(const void* g, void* l) {
  __builtin_amdgcn_global_load_lds(
      (const __attribute__((address_space(1))) void*)g,
      (__attribute__((address_space(3))) void*)l, 16, 0, 0);
}

// F(M) = sum_{j=0}^{M-1} floor(j/2^lg)
static __device__ __forceinline__ int Fpre(int M, int lg) {
  if (M <= 0) return 0;
  const int q = (M - 1) >> lg, r = (M - 1) & ((1 << lg) - 1);
  return ((q * (q - 1)) << (lg - 1)) + q * (r + 1);
}

// ---------------------------------------------------------------------------
// Pass 1 (fused): blocks [0,1024): A path -- convert 128-block (bi,kb) to
// tril bf16 for kb<=bi; ZERO Ab block for kb==bi+1 when bi even (the 256-row
// gemm A-tile reads one col-block past the top half's diagonal; tril = 0
// there, so Ab must hold real zeros). kb>bi+1: dead. Blocks [1024,3136):
// B -> Bt transpose (tril bf16) over the 2112 needed 64x64 tiles.
// (Strict-upper C zeroing moved to gemm tail items.)
// ---------------------------------------------------------------------------
__global__ __launch_bounds__(256) void convert_fused(
    const float* __restrict__ A, const float* __restrict__ B,
    u16* __restrict__ Ab, u16* __restrict__ Bt) {
  __shared__ float t[64][65];
  const int blk = blockIdx.x;
  const int tid = threadIdx.x;

  if (blk < 1024) {  // ---- A path: 128x128 block (bi, kb) ----
    const int kb = blk & 31, bi = blk >> 5;
    const int rr = tid >> 5;
    const int c4 = (tid & 31) * 4;
    if (kb > bi) {
      if (kb == bi + 1 && !(bi & 1)) {  // super-diagonal: real zeros
        const ushort4 z = {0, 0, 0, 0};
#pragma unroll
        for (int p = 0; p < 16; ++p)
          *(ushort4*)&Ab[(long)(bi * 128 + p * 8 + rr) * NN + kb * 128 + c4] =
              z;
      }
      return;
    }
    const bool diag = (kb == bi);
#pragma unroll
    for (int p = 0; p < 16; ++p) {
      const int row = p * 8 + rr;
      const long off = (long)(bi * 128 + row) * NN + kb * 128 + c4;
      float4 v = *(const float4*)&A[off];
      ushort4 o;
      if (diag) {
        const int i = bi * 128 + row, k = kb * 128 + c4;
        o.x = (k + 0 <= i) ? f2bf(v.x) : (u16)0;
        o.y = (k + 1 <= i) ? f2bf(v.y) : (u16)0;
        o.z = (k + 2 <= i) ? f2bf(v.z) : (u16)0;
        o.w = (k + 3 <= i) ? f2bf(v.w) : (u16)0;
      } else {
        o.x = f2bf(v.x); o.y = f2bf(v.y); o.z = f2bf(v.z); o.w = f2bf(v.w);
      }
      *(ushort4*)&Ab[off] = o;
    }
    return;
  }

  // ---- B path: pair-decoded 64x64 transpose tile (only needed ones) ----
  const int t4 = blk - 1024;  // 0..2111 = 528 pairs x 4 subtiles
  int prem = t4 >> 2, N = 0;
  while (prem >= 32 - N) { prem -= 32 - N; ++N; }
  const int K = N + prem;  // N <= K: 128-block (n=N, k=K) is needed
  const int sub = t4 & 3;
  const int n64 = 2 * N + (sub & 1);
  const int k64 = 2 * K + (sub >> 1);

  const int n0 = n64 * 64;
  const int k0 = k64 * 64;

  if (n0 > k0 + 63) {  // needed block, 64-tile fully above diagonal -> zeros
    const int n = tid >> 3;
    const int kc = (tid & 7) * 8;
    const uint4 z = {0u, 0u, 0u, 0u};
#pragma unroll
    for (int p = 0; p < 2; ++p)
      *(uint4*)&Bt[(long)(n0 + n + p * 32) * NN + k0 + kc] = z;
    return;
  }

#pragma unroll
  for (int p = 0; p < 4; ++p) {
    const int r = (tid >> 4) + p * 16;
    const int c = (tid & 15) * 4;
    float4 v = *(const float4*)&B[(long)(k0 + r) * NN + n0 + c];
    const int kg = k0 + r;
    t[r][c + 0] = (n0 + c + 0 <= kg) ? v.x : 0.f;
    t[r][c + 1] = (n0 + c + 1 <= kg) ? v.y : 0.f;
    t[r][c + 2] = (n0 + c + 2 <= kg) ? v.z : 0.f;
    t[r][c + 3] = (n0 + c + 3 <= kg) ? v.w : 0.f;
  }
  __syncthreads();

#pragma unroll
  for (int p = 0; p < 2; ++p) {
    const int n = (tid >> 3) + p * 32;
    const int kc = (tid & 7) * 8;
    union { u16 h[8]; uint4 v; } pk;
#pragma unroll
    for (int j = 0; j < 8; ++j) pk.h[j] = f2bf(t[kc + j][n]);
    *(uint4*)&Bt[(long)(n0 + n) * NN + k0 + kc] = pk.v;
  }
}

// ---------------------------------------------------------------------------
// Pass 2: lower-tri bf16 MFMA GEMM, 256x128 tile (intensity 87 FLOP/B vs
// 64 at 128^2 -- R10 proved smaller tiles lose; go bigger). 512 threads =
// 8 waves (4x2 grid of 64x64 wave-tiles), single 48 KB LDS buffer, m97
// 2-barrier loop, 2 blocks/CU (16 waves) co-resident. 6256 total K64-steps
// (vs 11968). Split-K chunks of 2^(lg+1) steps; longest-K-first items.
// Items >= nreal are strict-upper C zero-fill tiles (run in drain bubbles).
// Swizzled staging (pre-swizzled source col + XOR'd read slot): 0 conflicts.
// ---------------------------------------------------------------------------
__global__ __launch_bounds__(512, 4) void gemm_tril(
    const u16* __restrict__ Ab, const u16* __restrict__ Bt,
    float* __restrict__ C, float* __restrict__ P, int lg, int nreal) {
  __shared__ u16 As[256 * 64];  // 32 KB
  __shared__ u16 Bs[128 * 64];  // 16 KB

  const int tid = threadIdx.x;
  const int lane = tid & 63;
  const int wid = tid >> 6;  // 0..7
  const int wm = wid >> 1;   // 0..3
  const int wn = wid & 1;    // 0..1
  const int sm = lane >> 3;               // staging row within 8-row chunk
  const int sks = ((lane & 7) ^ sm) * 8;  // pre-swizzled source col (u16)
  const int rsel = lane & 7;              // fragment row & 7

  const int item = blockIdx.x;

  if (item >= nreal) {  // ---- zero-fill a strict-upper 256x128 C tile ----
    int zi = item - nreal, bi = 0;
    for (; bi < 15; ++bi) {
      const int u = 30 - 2 * bi;
      if (zi < u) break;
      zi -= u;
    }
    const int bj = 2 * bi + 2 + zi;
    const float4 z = {0.f, 0.f, 0.f, 0.f};
#pragma unroll
    for (int p = 0; p < 16; ++p) {
      const int idx = p * 512 + tid;  // float4 idx in 256x128 tile
      const int row = idx >> 5;
      const int col = (idx & 31) * 4;
      *(float4*)&C[(long)(bi * 256 + row) * NN + bj * 128 + col] = z;
    }
    return;
  }

  // ---- decode item -> (bi, bj, chunk); 256-rows longest-K-first ----
  // Row bi (desc): T = 2bi+2 tiles; items = T + Fpre(T,lg); tile bj has
  // 1 + ((T-bj-1)>>lg) chunks; L64 = 2*(T-bj) K64-steps.
  int rem = item, bi = 15, T = 32, slabpre = 0;
  for (int s = 0; s < 16; ++s) {
    bi = 15 - s;
    T = 2 * bi + 2;
    const int fp = Fpre(T, lg);
    const int g = T + fp;
    if (rem < g) break;
    rem -= g;
    slabpre += fp;
  }
  int bj = 0;
  for (;;) {
    const int c = 1 + ((T - bj - 1) >> lg);
    if (rem < c) break;
    rem -= c;
    ++bj;
  }
  const int chunk = rem;
  const int L64 = 2 * (T - bj);
  const int start = chunk << (lg + 1);
  const int nk = min(2 << lg, L64 - start);
  const int rA = bi * 256;
  const int rB = bj * 128;
  const long kbase = (long)bj * 128 + (long)start * 64;

  f32x4 acc[4][4];
#pragma unroll
  for (int i = 0; i < 4; ++i)
#pragma unroll
    for (int j = 0; j < 4; ++j) acc[i][j] = (f32x4){0.f, 0.f, 0.f, 0.f};

  for (int kt = 0; kt < nk; ++kt) {
    const long k0 = kbase + (long)kt * 64;
#pragma unroll
    for (int c = 0; c < 4; ++c) {  // A: 32 chunks of 8 rows x 64 bf16
      const int ch = wid * 4 + c;
      gload_lds16(Ab + ((long)(rA + ch * 8 + sm) * NN + k0 + sks),
                  &As[ch * 512]);
    }
#pragma unroll
    for (int c = 0; c < 2; ++c) {  // B: 16 chunks
      const int ch = wid * 2 + c;
      gload_lds16(Bt + ((long)(rB + ch * 8 + sm) * NN + k0 + sks),
                  &Bs[ch * 512]);
    }
    __syncthreads();  // vmcnt(0) drain; 2nd co-resident block covers stall

    bf16x8 a[2][4], b[2][4];
#pragma unroll
    for (int kk = 0; kk < 2; ++kk)
#pragma unroll
      for (int q = 0; q < 4; ++q) {
        const int fr = q * 16 + (lane & 15);                   // row in 64-blk
        const int slot = ((kk * 4 + (lane >> 4)) ^ rsel) * 8;  // swizzled col
        a[kk][q] = *(const bf16x8*)&As[(wm * 64 + fr) * 64 + slot];
        b[kk][q] = *(const bf16x8*)&Bs[(wn * 64 + fr) * 64 + slot];
      }
#pragma unroll
    for (int kk = 0; kk < 2; ++kk)
#pragma unroll
      for (int m4 = 0; m4 < 4; ++m4)
#pragma unroll
        for (int n4 = 0; n4 < 4; ++n4)
          acc[m4][n4] = __builtin_amdgcn_mfma_f32_16x16x32_bf16(
              a[kk][m4], b[kk][n4], acc[m4][n4], 0, 0, 0);
    __syncthreads();  // LDS free for next K-step
  }

  // ---- epilogue: C/D layout col=lane&15, row=(lane>>4)*4+r ----
  const int lrow = wm * 64 + (lane >> 4) * 4;
  const int lcol = wn * 64 + (lane & 15);
  if (chunk == 0) {
    const bool diag = (bj >= 2 * bi);  // tile contains the diagonal
#pragma unroll
    for (int m4 = 0; m4 < 4; ++m4)
#pragma unroll
      for (int n4 = 0; n4 < 4; ++n4)
#pragma unroll
        for (int r = 0; r < 4; ++r) {
          const int gi = rA + lrow + m4 * 16 + r;
          const int gj = rB + lcol + n4 * 16;
          float v = acc[m4][n4][r];
          if (diag && gj > gi) v = 0.f;
          C[(long)gi * NN + gj] = v;
        }
  } else {
    const int slabidx =
        slabpre + (Fpre(T, lg) - Fpre(T - bj, lg)) + (chunk - 1);
    float* slab = P + (long)slabidx * 32768;  // 256x128 fp32 = 128 KB
#pragma unroll
    for (int m4 = 0; m4 < 4; ++m4)
#pragma unroll
      for (int n4 = 0; n4 < 4; ++n4)
#pragma unroll
        for (int r = 0; r < 4; ++r)
          slab[(lrow + m4 * 16 + r) * 128 + lcol + n4 * 16] = acc[m4][n4][r];
  }
}

// ---------------------------------------------------------------------------
// Pass 3: add partial slabs into C. Grid = multi-chunk tiles only (bj <
// T - 2^lg per row): 156 (lg=3) / 72 (lg=4).
// ---------------------------------------------------------------------------
__global__ __launch_bounds__(256) void reduce_partials(
    float* __restrict__ C, const float* __restrict__ P, int lg) {
  const int H = 1 << lg;
  int rem = blockIdx.x, bi = 15, T = 32, slabpre = 0;
  for (int s = 0; s < 16; ++s) {
    bi = 15 - s;
    T = 2 * bi + 2;
    const int g = (T - H > 0) ? (T - H) : 0;
    if (rem < g) break;
    rem -= g;
    slabpre += Fpre(T, lg);
  }
  const int bj = rem;  // bj < T - H  -> nch >= 2
  const int nch = 1 + ((T - bj - 1) >> lg);
  const int slaboff = slabpre + (Fpre(T, lg) - Fpre(T - bj, lg));

  const int tid = threadIdx.x;
#pragma unroll
  for (int p = 0; p < 32; ++p) {
    const int idx = p * 256 + tid;  // float4 idx in 256x128 tile (0..8191)
    const int row = idx >> 5;
    const int col = (idx & 31) * 4;
    const long coff = (long)(bi * 256 + row) * NN + bj * 128 + col;
    float4 acc = *(const float4*)&C[coff];
    for (int e = 0; e < nch - 1; ++e) {
      const float4 q =
          *(const float4*)&P[(long)(slaboff + e) * 32768 + row * 128 + col];
      acc.x += q.x; acc.y += q.y; acc.z += q.z; acc.w += q.w;
    }
    *(float4*)&C[coff] = acc;
  }
}

// ---------------------------------------------------------------------------
// Fallback (ws too small): naive fp32.
// ---------------------------------------------------------------------------
__global__ void naive_tril(const float* __restrict__ A,
                           const float* __restrict__ B, float* __restrict__ C) {
  const int j = blockIdx.x * 256 + threadIdx.x;
  const int i = blockIdx.y;
  float s = 0.f;
  for (int k = j; k <= i; ++k) s += A[(long)i * NN + k] * B[(long)k * NN + j];
  C[(long)i * NN + j] = s;
}

extern "C" void kernel_launch(void* const* d_in, const int* in_sizes, int n_in,
                              void* d_out, int out_size, void* d_ws,
                              size_t ws_size, hipStream_t stream) {
  const float* A = (const float*)d_in[0];
  const float* B = (const float*)d_in[1];
  float* C = (float*)d_out;

  const size_t opbytes = (size_t)2 * NN * NN * sizeof(u16);  // 64 MB operands
  // tiers (chunk = 2^(lg+1) K64-steps; slab = 256x128 fp32 = 128 KB):
  //   lg=3 (K=1024): 520 real items, 248 slabs (31.7 MB), 156 reduce tiles
  //   lg=4 (K=2048): 344 real items,  72 slabs ( 9.2 MB),  72 reduce tiles
  //   lg=5 (K=4096): 272 real items,   0 slabs
  const size_t need3 = opbytes + (size_t)248 * 131072;
  const size_t need4 = opbytes + (size_t)72 * 131072;

  if (ws_size < opbytes) {
    naive_tril<<<dim3(16, NN), 256, 0, stream>>>(A, B, C);
    return;
  }

  int lg, nreal, nred;
  if (ws_size >= need3)      { lg = 3; nreal = 520; nred = 156; }
  else if (ws_size >= need4) { lg = 4; nreal = 344; nred = 72; }
  else                       { lg = 5; nreal = 272; nred = 0; }

  u16* Ab = (u16*)d_ws;
  u16* Bt = Ab + (long)NN * NN;
  float* P = (float*)((char*)d_ws + opbytes);

  convert_fused<<<3136, 256, 0, stream>>>(A, B, Ab, Bt);
  gemm_tril<<<nreal + 240, 512, 0, stream>>>(Ab, Bt, C, P, lg, nreal);
  if (nred > 0) reduce_partials<<<nred, 256, 0, stream>>>(C, P, lg);
}

// Round 12
// 89.809 us; speedup vs baseline: 1.2161x; 1.1155x over previous
//
#include <hip/hip_runtime.h>
#include <hip/hip_bf16.h>

#define NN 4096

typedef unsigned short u16;
typedef __attribute__((ext_vector_type(8))) short bf16x8;
typedef __attribute__((ext_vector_type(4))) float f32x4;

// fp32 -> bf16 round-to-nearest-even (inputs finite N(0,1))
static __device__ __forceinline__ u16 f2bf(float x) {
  unsigned u = __float_as_uint(x);
  u += 0x7fff + ((u >> 16) & 1);
  return (u16)(u >> 16);
}

// async global->LDS, 16B per lane; LDS dest = wave-uniform base + lane*16
static __device__ __forceinline__ void gload_lds16(const void* g, void* l) {
  __builtin_amdgcn_global_load_lds(
      (const __attribute__((address_space(1))) void*)g,
      (__attribute__((address_space(3))) void*)l, 16, 0, 0);
}

// F(M) = sum_{j=0}^{M-1} floor(j/2^lg)
static __device__ __forceinline__ int Fpre(int M, int lg) {
  if (M <= 0) return 0;
  const int q = (M - 1) >> lg, r = (M - 1) & ((1 << lg) - 1);
  return ((q * (q - 1)) << (lg - 1)) + q * (r + 1);
}

// ---------------------------------------------------------------------------
// Pass 1 (fused, grid 3200):
//  [0,1024):    A path, 128-block (bi,kb). kb<=bi: tril bf16 convert.
//               kb>bi: zero C block (bi,kb) (strict-upper C), and for
//               kb==bi+1 with bi even also zero the Ab block (the 256-row
//               gemm A-tile reads one 128-col past the top half's diagonal).
//  [1024,3136): B -> Bt transpose (tril bf16), 2112 needed 64x64 tiles.
//  [3136,3200): zero sub-diagonal Bt 128-blocks (n128=2q+1,k128=2q) -- the
//               256-row B-tile's lower half reads one 128-col before its
//               diagonal; tril(B)^T = 0 there, Bt must hold real zeros.
// ---------------------------------------------------------------------------
__global__ __launch_bounds__(256) void convert_fused(
    const float* __restrict__ A, const float* __restrict__ B,
    u16* __restrict__ Ab, u16* __restrict__ Bt, float* __restrict__ C) {
  __shared__ float t[64][65];
  const int blk = blockIdx.x;
  const int tid = threadIdx.x;

  if (blk < 1024) {  // ---- A path ----
    const int kb = blk & 31, bi = blk >> 5;
    const int rr = tid >> 5;
    if (kb > bi) {
      const float4 z = {0.f, 0.f, 0.f, 0.f};
      const int c4 = (tid & 31);
#pragma unroll
      for (int p = 0; p < 16; ++p)
        ((float4*)&C[(long)(bi * 128 + p * 8 + rr) * NN + kb * 128])[c4] = z;
      if (kb == bi + 1 && !(bi & 1)) {  // super-diagonal Ab: real zeros
        const ushort4 zz = {0, 0, 0, 0};
        const int c4b = (tid & 31) * 4;
#pragma unroll
        for (int p = 0; p < 16; ++p)
          *(ushort4*)&Ab[(long)(bi * 128 + p * 8 + rr) * NN + kb * 128 + c4b] =
              zz;
      }
      return;
    }
    const int c4 = (tid & 31) * 4;
    const bool diag = (kb == bi);
#pragma unroll
    for (int p = 0; p < 16; ++p) {
      const int row = p * 8 + rr;
      const long off = (long)(bi * 128 + row) * NN + kb * 128 + c4;
      float4 v = *(const float4*)&A[off];
      ushort4 o;
      if (diag) {
        const int i = bi * 128 + row, k = kb * 128 + c4;
        o.x = (k + 0 <= i) ? f2bf(v.x) : (u16)0;
        o.y = (k + 1 <= i) ? f2bf(v.y) : (u16)0;
        o.z = (k + 2 <= i) ? f2bf(v.z) : (u16)0;
        o.w = (k + 3 <= i) ? f2bf(v.w) : (u16)0;
      } else {
        o.x = f2bf(v.x); o.y = f2bf(v.y); o.z = f2bf(v.z); o.w = f2bf(v.w);
      }
      *(ushort4*)&Ab[off] = o;
    }
    return;
  }

  if (blk >= 3136) {  // ---- sub-diagonal Bt zero blocks ----
    const int idx = blk - 3136;  // 0..63
    const int q = idx >> 2;
    const int n0 = (2 * (2 * q + 1) + (idx & 1)) * 64;
    const int k0 = (2 * (2 * q) + ((idx >> 1) & 1)) * 64;
    const int n = tid >> 3;
    const int kc = (tid & 7) * 8;
    const uint4 z = {0u, 0u, 0u, 0u};
#pragma unroll
    for (int p = 0; p < 2; ++p)
      *(uint4*)&Bt[(long)(n0 + n + p * 32) * NN + k0 + kc] = z;
    return;
  }

  // ---- B path: pair-decoded 64x64 transpose tile ----
  const int t4 = blk - 1024;  // 0..2111
  int prem = t4 >> 2, N = 0;
  while (prem >= 32 - N) { prem -= 32 - N; ++N; }
  const int K = N + prem;  // N <= K
  const int sub = t4 & 3;
  const int n0 = (2 * N + (sub & 1)) * 64;
  const int k0 = (2 * K + (sub >> 1)) * 64;

  if (n0 > k0 + 63) {  // fully above diagonal -> zeros
    const int n = tid >> 3;
    const int kc = (tid & 7) * 8;
    const uint4 z = {0u, 0u, 0u, 0u};
#pragma unroll
    for (int p = 0; p < 2; ++p)
      *(uint4*)&Bt[(long)(n0 + n + p * 32) * NN + k0 + kc] = z;
    return;
  }

#pragma unroll
  for (int p = 0; p < 4; ++p) {
    const int r = (tid >> 4) + p * 16;
    const int c = (tid & 15) * 4;
    float4 v = *(const float4*)&B[(long)(k0 + r) * NN + n0 + c];
    const int kg = k0 + r;
    t[r][c + 0] = (n0 + c + 0 <= kg) ? v.x : 0.f;
    t[r][c + 1] = (n0 + c + 1 <= kg) ? v.y : 0.f;
    t[r][c + 2] = (n0 + c + 2 <= kg) ? v.z : 0.f;
    t[r][c + 3] = (n0 + c + 3 <= kg) ? v.w : 0.f;
  }
  __syncthreads();

#pragma unroll
  for (int p = 0; p < 2; ++p) {
    const int n = (tid >> 3) + p * 32;
    const int kc = (tid & 7) * 8;
    union { u16 h[8]; uint4 v; } pk;
#pragma unroll
    for (int j = 0; j < 8; ++j) pk.h[j] = f2bf(t[kc + j][n]);
    *(uint4*)&Bt[(long)(n0 + n) * NN + k0 + kc] = pk.v;
  }
}

// ---------------------------------------------------------------------------
// Pass 2: 8-phase-style tril GEMM. 256x256 tile, BK=64, 8 waves (2x4; per
// wave 128x64 out, acc[8][4] f32x4). 128 KB dbuf LDS (dynamic), 1 block/CU.
// Per K64-step: issue 8 stage loads for t+1, counted vmcnt(8) (never 0 in
// loop), barrier, then 4 phases {ds_read frags; barrier; lgkmcnt(0)+
// sched_barrier; setprio(1) 16 MFMA setprio(0); barrier} (T3+T4+T5).
// T2: pre-swizzled global source col + XOR'd read slot -> 0 conflicts.
// Split-K chunks of 4<<lg K64-steps; chunk 0 -> C, else -> slab.
// ---------------------------------------------------------------------------
__global__ __launch_bounds__(512, 2) void gemm_tril(
    const u16* __restrict__ Ab, const u16* __restrict__ Bt,
    float* __restrict__ C, float* __restrict__ P, int lg) {
  extern __shared__ u16 lds[];  // [2][16384] A | [2][16384] B = 128 KB
  u16* AsB = lds;
  u16* BsB = lds + 32768;

  const int tid = threadIdx.x;
  const int lane = tid & 63;
  const int wid = tid >> 6;  // 0..7
  const int wm = wid >> 2;   // 0..1 (128-row half)
  const int wn = wid & 3;    // 0..3 (64-col block)
  const int sm = lane >> 3;
  const int sks = ((lane & 7) ^ sm) * 8;  // pre-swizzled source col (u16)
  const int rsel = lane & 7;

  // ---- decode blockIdx.x -> (bi, bj, chunk); 256-rows longest-K-first ----
  int rem = blockIdx.x, bi = 15, slabpre = 0;
  for (int s = 0; s < 16; ++s) {
    bi = 15 - s;
    const int fp = Fpre(bi + 1, lg);
    const int g = (bi + 1) + fp;
    if (rem < g) break;
    rem -= g;
    slabpre += fp;
  }
  int bj = 0;
  for (;;) {
    const int c = ((bi - bj) >> lg) + 1;  // chunks of tile (bi,bj)
    if (rem < c) break;
    rem -= c;
    ++bj;
  }
  const int chunk = rem;
  const int L64 = 4 * (bi - bj + 1);
  const int H64 = 4 << lg;
  const int start = chunk * H64;
  const int nk = min(H64, L64 - start);
  const int rA = bi * 256;
  const int rB = bj * 256;
  const long kbase = (long)bj * 256 + (long)start * 64;

  f32x4 acc[8][4];
#pragma unroll
  for (int i = 0; i < 8; ++i)
#pragma unroll
    for (int j = 0; j < 4; ++j) acc[i][j] = (f32x4){0.f, 0.f, 0.f, 0.f};

  // stage K64-step kt into buffer b: 8 gload_lds16 per thread
#define STAGE(kt, b)                                                         \
  do {                                                                       \
    const long k0 = kbase + (long)(kt)*64;                                   \
    _Pragma("unroll") for (int c = 0; c < 4; ++c) {                          \
      const int ch = wid * 4 + c;                                            \
      gload_lds16(Ab + ((long)(rA + ch * 8 + sm) * NN + k0 + sks),           \
                  AsB + (b)*16384 + ch * 512);                               \
      gload_lds16(Bt + ((long)(rB + ch * 8 + sm) * NN + k0 + sks),           \
                  BsB + (b)*16384 + ch * 512);                               \
    }                                                                        \
  } while (0)

  STAGE(0, 0);

  for (int kt = 0; kt < nk; ++kt) {
    const int cur = kt & 1;
    if (kt + 1 < nk) {
      STAGE(kt + 1, cur ^ 1);  // 8 loads stay in flight across barriers
      asm volatile("s_waitcnt vmcnt(8)" ::: "memory");  // cur's 8 landed
    } else {
      asm volatile("s_waitcnt vmcnt(0)" ::: "memory");
    }
    __builtin_amdgcn_s_barrier();  // buf[cur] staged by all waves

    const u16* As = AsB + cur * 16384;
    const u16* Bs = BsB + cur * 16384;

    bf16x8 bb[4][2];
#pragma unroll
    for (int p = 0; p < 4; ++p) {  // phase p: m-reps {2p, 2p+1}
      bf16x8 aa[2][2];
#pragma unroll
      for (int mm = 0; mm < 2; ++mm)
#pragma unroll
        for (int kk = 0; kk < 2; ++kk) {
          const int fr = wm * 128 + (2 * p + mm) * 16 + (lane & 15);
          const int slot = ((kk * 4 + (lane >> 4)) ^ rsel) * 8;
          aa[mm][kk] = *(const bf16x8*)&As[fr * 64 + slot];
        }
      if (p == 0) {
#pragma unroll
        for (int n4 = 0; n4 < 4; ++n4)
#pragma unroll
          for (int kk = 0; kk < 2; ++kk) {
            const int fr = wn * 64 + n4 * 16 + (lane & 15);
            const int slot = ((kk * 4 + (lane >> 4)) ^ rsel) * 8;
            bb[n4][kk] = *(const bf16x8*)&Bs[fr * 64 + slot];
          }
      }
      __builtin_amdgcn_s_barrier();
      asm volatile("s_waitcnt lgkmcnt(0)" ::: "memory");
      __builtin_amdgcn_sched_barrier(0);
      __builtin_amdgcn_s_setprio(1);
#pragma unroll
      for (int kk = 0; kk < 2; ++kk)
#pragma unroll
        for (int mm = 0; mm < 2; ++mm)
#pragma unroll
          for (int n4 = 0; n4 < 4; ++n4)
            acc[2 * p + mm][n4] = __builtin_amdgcn_mfma_f32_16x16x32_bf16(
                aa[mm][kk], bb[n4][kk], acc[2 * p + mm][n4], 0, 0, 0);
      __builtin_amdgcn_s_setprio(0);
      __builtin_amdgcn_s_barrier();  // phase-end; also guards next STAGE
    }
  }
#undef STAGE

  // ---- epilogue: C/D layout col=lane&15, row=(lane>>4)*4+r ----
  const int lrow = wm * 128 + (lane >> 4) * 4;
  const int lcol = wn * 64 + (lane & 15);
  if (chunk == 0) {
    const bool diag = (bi == bj);
#pragma unroll
    for (int m4 = 0; m4 < 8; ++m4)
#pragma unroll
      for (int n4 = 0; n4 < 4; ++n4)
#pragma unroll
        for (int r = 0; r < 4; ++r) {
          const int gi = rA + lrow + m4 * 16 + r;
          const int gj = rB + lcol + n4 * 16;
          float v = acc[m4][n4][r];
          if (diag && gj > gi) v = 0.f;
          C[(long)gi * NN + gj] = v;
        }
  } else {
    const int slabidx =
        slabpre + (Fpre(bi + 1, lg) - Fpre(bi - bj + 1, lg)) + (chunk - 1);
    float* slab = P + (long)slabidx * 65536;  // 256x256 fp32 = 256 KB
#pragma unroll
    for (int m4 = 0; m4 < 8; ++m4)
#pragma unroll
      for (int n4 = 0; n4 < 4; ++n4)
#pragma unroll
        for (int r = 0; r < 4; ++r)
          slab[(lrow + m4 * 16 + r) * 256 + lcol + n4 * 16] = acc[m4][n4][r];
  }
}

// ---------------------------------------------------------------------------
// Pass 3: add partial slabs into C. Multi-chunk tiles only (bi-bj >= 2^lg),
// 4 row-stripes per tile: grid = nred*4.
// ---------------------------------------------------------------------------
__global__ __launch_bounds__(256) void reduce_partials(
    float* __restrict__ C, const float* __restrict__ P, int lg) {
  const int G = 1 << lg;
  const int tb = blockIdx.x >> 2;
  const int stripe = blockIdx.x & 3;
  int rem = tb, bi = 15, slabpre = 0;
  for (int s = 0; s < 16; ++s) {
    bi = 15 - s;
    const int g = (bi + 1 - G > 0) ? bi + 1 - G : 0;
    if (rem < g) break;
    rem -= g;
    slabpre += Fpre(bi + 1, lg);
  }
  const int bj = rem;  // bj <= bi-G -> nch >= 2
  const int nch = ((bi - bj) >> lg) + 1;
  const int slaboff = slabpre + (Fpre(bi + 1, lg) - Fpre(bi - bj + 1, lg));

  const int tid = threadIdx.x;
#pragma unroll
  for (int p = 0; p < 16; ++p) {
    const int idx = p * 256 + tid;  // 4096 float4 per 64-row stripe
    const int row = stripe * 64 + (idx >> 6);
    const int col = (idx & 63) * 4;
    const long coff = (long)(bi * 256 + row) * NN + bj * 256 + col;
    float4 acc = *(const float4*)&C[coff];
    for (int e = 0; e < nch - 1; ++e) {
      const float4 q =
          *(const float4*)&P[(long)(slaboff + e) * 65536 + row * 256 + col];
      acc.x += q.x; acc.y += q.y; acc.z += q.z; acc.w += q.w;
    }
    *(float4*)&C[coff] = acc;
  }
}

// ---------------------------------------------------------------------------
// Fallback (ws too small): naive fp32.
// ---------------------------------------------------------------------------
__global__ void naive_tril(const float* __restrict__ A,
                           const float* __restrict__ B, float* __restrict__ C) {
  const int j = blockIdx.x * 256 + threadIdx.x;
  const int i = blockIdx.y;
  float s = 0.f;
  for (int k = j; k <= i; ++k) s += A[(long)i * NN + k] * B[(long)k * NN + j];
  C[(long)i * NN + j] = s;
}

extern "C" void kernel_launch(void* const* d_in, const int* in_sizes, int n_in,
                              void* d_out, int out_size, void* d_ws,
                              size_t ws_size, hipStream_t stream) {
  const float* A = (const float*)d_in[0];
  const float* B = (const float*)d_in[1];
  float* C = (float*)d_out;

  const size_t opbytes = (size_t)2 * NN * NN * sizeof(u16);  // 64 MB operands
  // tiers (chunk = 4<<lg K64-steps; slab = 256x256 fp32 = 256 KB):
  //   lg=2 (K=1024): 260 items, 124 slabs (32.5 MB), 78 reduce tiles
  //   lg=3 (K=2048): 172 items,  36 slabs ( 9.4 MB), 36 reduce tiles
  //   lg=4 (K=4096): 136 items,   0 slabs
  const size_t needA = opbytes + (size_t)124 * 262144;
  const size_t needB = opbytes + (size_t)36 * 262144;

  if (ws_size < opbytes) {
    naive_tril<<<dim3(16, NN), 256, 0, stream>>>(A, B, C);
    return;
  }

  int lg, nitems, nred;
  if (ws_size >= needA)      { lg = 2; nitems = 260; nred = 78; }
  else if (ws_size >= needB) { lg = 3; nitems = 172; nred = 36; }
  else                       { lg = 4; nitems = 136; nred = 0; }

  u16* Ab = (u16*)d_ws;
  u16* Bt = Ab + (long)NN * NN;
  float* P = (float*)((char*)d_ws + opbytes);

  hipFuncSetAttribute((const void*)gemm_tril,
                      hipFuncAttributeMaxDynamicSharedMemorySize, 131072);

  convert_fused<<<3200, 256, 0, stream>>>(A, B, Ab, Bt, C);
  gemm_tril<<<nitems, 512, 131072, stream>>>(Ab, Bt, C, P, lg);
  if (nred > 0) reduce_partials<<<nred * 4, 256, 0, stream>>>(C, P, lg);
}